// Round 5
// baseline (445.158 us; speedup 1.0000x reference)
//
#include <hip/hip_runtime.h>
#include <hip/hip_bf16.h>
#include <cstdio>

typedef __bf16 bf16_t;
typedef __bf16 bf16x8 __attribute__((ext_vector_type(8)));
typedef __bf16 bf16x4 __attribute__((ext_vector_type(4)));
typedef float  f32x16 __attribute__((ext_vector_type(16)));

#define TM 128
#define TN 128
#define BK 64

// f32 -> bf16 convert, 4 elems/thread, grid-stride
__global__ __launch_bounds__(256)
void cvt_f32_bf16(const float* __restrict__ in, bf16_t* __restrict__ out, int n)
{
    for (int i = (blockIdx.x * 256 + threadIdx.x) * 4; i < n; i += gridDim.x * 256 * 4) {
        const float4 v = *(const float4*)(in + i);
        bf16x4 o;
        o[0] = (bf16_t)v.x; o[1] = (bf16_t)v.y; o[2] = (bf16_t)v.z; o[3] = (bf16_t)v.w;
        *(bf16x4*)(out + i) = o;
    }
}

// ---- BK=64 staging ---------------------------------------------------------
// LDS tile: 128 rows x 64 bf16 (128 B = 8 chunks of 16 B).
// Chunk c of row r lives at slot c ^ (r & 7) (XOR swizzle).
// global_load_lds: HW scatters lane i to (wave-uniform dest) + i*16B, so the
// dest we pass depends only on (p, w); the per-lane GLOBAL source address
// carries the swizzle. Lane i's effective LDS chunk index = p*256 + w*64 + i.
__device__ __forceinline__ void stage2(const bf16_t* __restrict__ Ab,
                                       const bf16_t* __restrict__ Bb,
                                       bf16_t* As, bf16_t* Bs,
                                       int k0, int K, int t, int w)
{
#pragma unroll
    for (int p = 0; p < 4; p++) {
        const int idx = p * 256 + t;          // this lane's 16B-chunk index
        const int row = idx >> 3;
        const int c   = (idx & 7) ^ (row & 7);
        bf16_t* dstA = As + (p * 256 + w * 64) * 8;   // wave-uniform
        bf16_t* dstB = Bs + (p * 256 + w * 64) * 8;
        __builtin_amdgcn_global_load_lds(
            (const __attribute__((address_space(1))) void*)(Ab + (size_t)row * K + k0 + c * 8),
            (__attribute__((address_space(3))) void*)dstA, 16, 0, 0);
        __builtin_amdgcn_global_load_lds(
            (const __attribute__((address_space(1))) void*)(Bb + (size_t)row * K + k0 + c * 8),
            (__attribute__((address_space(3))) void*)dstB, 16, 0, 0);
    }
}

// fragment read: row within 128, chunk c in [0,8) -> LDS element index
__device__ __forceinline__ int fidx(int row, int c)
{
    return row * 64 + ((c ^ (row & 7)) * 8);
}

#define ACC_INIT(acc)                                            \
    _Pragma("unroll") for (int i = 0; i < 2; i++)                \
    _Pragma("unroll") for (int j = 0; j < 2; j++)                \
    _Pragma("unroll") for (int e = 0; e < 16; e++) acc[i][j][e] = 0.f;

// ---- scores GEMM: C = (A @ Bm^T) * scale, bf16 write -----------------------
__global__ __launch_bounds__(256)
void gemm_scores(const bf16_t* __restrict__ A, const bf16_t* __restrict__ Bm,
                 bf16_t* __restrict__ C, float scale, int Ncols, int K,
                 long long strideA, long long strideB, long long strideC,
                 int tiles_m, int tiles_n)
{
    __shared__ bf16_t As[TM * BK];
    __shared__ bf16_t Bs[TN * BK];

    const int t    = threadIdx.x;
    const int w    = t >> 6;
    const int lane = t & 63;
    const int wm = w >> 1, wn = w & 1;
    const int lm = lane & 31;
    const int lk = lane >> 5;

    const int per_batch = tiles_m * tiles_n;
    const int batch = blockIdx.x / per_batch;
    const int rest  = blockIdx.x % per_batch;
    const int tm    = rest % tiles_m;
    const int tn    = rest / tiles_m;

    const bf16_t* Ab = A + (size_t)batch * strideA + (size_t)tm * TM * K;
    const bf16_t* Bb = Bm + (size_t)batch * strideB + (size_t)tn * TN * K;

    f32x16 acc[2][2];
    ACC_INIT(acc)

    for (int k0 = 0; k0 < K; k0 += BK) {
        stage2(Ab, Bb, As, Bs, k0, K, t, w);
        __syncthreads();
#pragma unroll
        for (int ks = 0; ks < 4; ks++) {
            const int c = ks * 2 + lk;
            bf16x8 af[2], bf[2];
#pragma unroll
            for (int mt = 0; mt < 2; mt++)
                af[mt] = *(const bf16x8*)&As[fidx(wm * 64 + mt * 32 + lm, c)];
#pragma unroll
            for (int nt = 0; nt < 2; nt++)
                bf[nt] = *(const bf16x8*)&Bs[fidx(wn * 64 + nt * 32 + lm, c)];
#pragma unroll
            for (int mt = 0; mt < 2; mt++)
#pragma unroll
                for (int nt = 0; nt < 2; nt++)
                    acc[mt][nt] = __builtin_amdgcn_mfma_f32_32x32x16_bf16(
                        af[mt], bf[nt], acc[mt][nt], 0, 0, 0);
        }
        __syncthreads();
    }

    // 32x32 C/D: col = lane&31, row = (reg&3) + 8*(reg>>2) + 4*(lane>>5)
#pragma unroll
    for (int mt = 0; mt < 2; mt++)
#pragma unroll
        for (int nt = 0; nt < 2; nt++) {
            const int colg = tn * TN + wn * 64 + nt * 32 + lm;
#pragma unroll
            for (int rg = 0; rg < 4; rg++) {
                const int rowg = tm * TM + wm * 64 + mt * 32 + rg * 8 + 4 * lk;
                bf16_t* p = C + (size_t)batch * strideC + (size_t)rowg * Ncols + colg;
#pragma unroll
                for (int j = 0; j < 4; j++)
                    p[(size_t)j * Ncols] = (bf16_t)(acc[mt][nt][rg * 4 + j] * scale);
            }
        }
}

// ---- fused key/value GEMM ---------------------------------------------------
__global__ __launch_bounds__(256)
void gemm_kv(const bf16_t* __restrict__ A,
             const bf16_t* __restrict__ Wa, const bf16_t* __restrict__ Wo,
             const float* __restrict__ ba, const float* __restrict__ bo,
             bf16_t* __restrict__ key, bf16_t* __restrict__ vT,
             int Nn, int Dd, int K)
{
    __shared__ bf16_t As[TM * BK];
    __shared__ bf16_t Bs[TN * BK];

    const int t    = threadIdx.x;
    const int w    = t >> 6;
    const int lane = t & 63;
    const int wm = w >> 1, wn = w & 1;
    const int lm = lane & 31;
    const int lk = lane >> 5;

    const int tiles_m = Nn / TM;             // 16
    const int per_batch = tiles_m * 16;      // 8 key-tiles + 8 value-tiles
    const int batch = blockIdx.x / per_batch;
    const int rest  = blockIdx.x % per_batch;
    const int tm    = rest % tiles_m;
    const int tn    = rest / tiles_m;
    const bool isK  = (tn < 8);

    const bf16_t* Ab = A + (size_t)batch * Nn * K + (size_t)tm * TM * K;
    const bf16_t* Bb = (isK ? Wa + (size_t)tn * TN * K
                            : Wo + (size_t)(tn - 8) * TN * K);
    const float* bias = isK ? ba : bo;

    f32x16 acc[2][2];
    ACC_INIT(acc)

    for (int k0 = 0; k0 < K; k0 += BK) {
        stage2(Ab, Bb, As, Bs, k0, K, t, w);
        __syncthreads();
#pragma unroll
        for (int ks = 0; ks < 4; ks++) {
            const int c = ks * 2 + lk;
            bf16x8 af[2], bf[2];
#pragma unroll
            for (int mt = 0; mt < 2; mt++)
                af[mt] = *(const bf16x8*)&As[fidx(wm * 64 + mt * 32 + lm, c)];
#pragma unroll
            for (int nt = 0; nt < 2; nt++)
                bf[nt] = *(const bf16x8*)&Bs[fidx(wn * 64 + nt * 32 + lm, c)];
#pragma unroll
            for (int mt = 0; mt < 2; mt++)
#pragma unroll
                for (int nt = 0; nt < 2; nt++)
                    acc[mt][nt] = __builtin_amdgcn_mfma_f32_32x32x16_bf16(
                        af[mt], bf[nt], acc[mt][nt], 0, 0, 0);
        }
        __syncthreads();
    }

#pragma unroll
    for (int mt = 0; mt < 2; mt++)
#pragma unroll
        for (int nt = 0; nt < 2; nt++) {
            const int cw = (tn & 7) * TN + wn * 64 + nt * 32 + lm;  // col in [0,1024)
            const float bv = bias[cw];                               // per-col: same for all j
#pragma unroll
            for (int rg = 0; rg < 4; rg++) {
                const int rowg = tm * TM + wm * 64 + mt * 32 + rg * 8 + 4 * lk;
                if (isK) {
                    bf16_t* p = key + (size_t)batch * Nn * Dd + (size_t)rowg * Dd + cw;
#pragma unroll
                    for (int j = 0; j < 4; j++)
                        p[(size_t)j * Dd] = (bf16_t)(acc[mt][nt][rg * 4 + j] + bv);
                } else {
                    bf16_t* p = vT + (size_t)batch * Dd * Nn + (size_t)cw * Nn + rowg;
                    bf16x4 pk;
#pragma unroll
                    for (int j = 0; j < 4; j++)
                        pk[j] = (bf16_t)(acc[mt][nt][rg * 4 + j] + bv);
                    *(bf16x4*)p = pk;
                }
            }
        }
}

// ---- per-row stats: m = max, rl = 1/sum(exp(x-m)) --------------------------
__global__ __launch_bounds__(256)
void row_stats(const bf16_t* __restrict__ S, float* __restrict__ M,
               float* __restrict__ RL)
{
    __shared__ float red[8];
    const int t = threadIdx.x;
    const int w = t >> 6;
    const int lane = t & 63;
    const bf16_t* p = S + (size_t)blockIdx.x * 2048;

    bf16x8 v = *(const bf16x8*)&p[t * 8];
    float x[8];
    float m = -1e30f;
#pragma unroll
    for (int i = 0; i < 8; i++) { x[i] = (float)v[i]; m = fmaxf(m, x[i]); }
#pragma unroll
    for (int off = 32; off >= 1; off >>= 1) m = fmaxf(m, __shfl_xor(m, off));
    if (lane == 0) red[w] = m;
    __syncthreads();
    m = fmaxf(fmaxf(red[0], red[1]), fmaxf(red[2], red[3]));

    float s = 0.f;
#pragma unroll
    for (int i = 0; i < 8; i++) s += __expf(x[i] - m);
#pragma unroll
    for (int off = 32; off >= 1; off >>= 1) s += __shfl_xor(s, off);
    if (lane == 0) red[4 + w] = s;
    __syncthreads();
    if (t == 0) {
        M[blockIdx.x]  = m;
        RL[blockIdx.x] = 1.f / (red[4] + red[5] + red[6] + red[7]);
    }
}

// ---- out GEMM with fused softmax -------------------------------------------
// out[b,q,o] = ( sum_k exp(S[b,q,k]-m[b,q]) * V[b,k,o] ) * rl[b,q]
__global__ __launch_bounds__(256)
void gemm_out(const bf16_t* __restrict__ S, const bf16_t* __restrict__ vT,
              const float* __restrict__ M, const float* __restrict__ RL,
              float* __restrict__ out, int Nn, int Dd)
{
    __shared__ bf16_t As[TM * BK];
    __shared__ bf16_t Bs[TN * BK];

    const int t    = threadIdx.x;
    const int w    = t >> 6;
    const int lane = t & 63;
    const int wm = w >> 1, wn = w & 1;
    const int lm = lane & 31;
    const int lk = lane >> 5;

    const int tiles_m = Nn / TM;               // 16
    const int tiles_n = Dd / TN;               // 8
    const int per_batch = tiles_m * tiles_n;
    const int batch = blockIdx.x / per_batch;
    const int rest  = blockIdx.x % per_batch;
    const int tm    = rest % tiles_m;
    const int tn    = rest / tiles_m;

    const int K = Nn;   // 2048
    const bf16_t* Ab = S + (size_t)batch * Nn * Nn + (size_t)tm * TM * K;
    const bf16_t* Bb = vT + (size_t)batch * Dd * Nn + (size_t)tn * TN * K;

    // per-lane row max for the two A row-fragments this lane reads
    float mr[2];
#pragma unroll
    for (int mt = 0; mt < 2; mt++)
        mr[mt] = M[(size_t)batch * Nn + tm * TM + wm * 64 + mt * 32 + lm];

    f32x16 acc[2][2];
    ACC_INIT(acc)

    for (int k0 = 0; k0 < K; k0 += BK) {
        stage2(Ab, Bb, As, Bs, k0, K, t, w);
        __syncthreads();
#pragma unroll
        for (int ks = 0; ks < 4; ks++) {
            const int c = ks * 2 + lk;
            bf16x8 af[2], bf[2];
#pragma unroll
            for (int mt = 0; mt < 2; mt++) {
                bf16x8 raw = *(const bf16x8*)&As[fidx(wm * 64 + mt * 32 + lm, c)];
                bf16x8 e;
#pragma unroll
                for (int j = 0; j < 8; j++)
                    e[j] = (bf16_t)__expf((float)raw[j] - mr[mt]);
                af[mt] = e;
            }
#pragma unroll
            for (int nt = 0; nt < 2; nt++)
                bf[nt] = *(const bf16x8*)&Bs[fidx(wn * 64 + nt * 32 + lm, c)];
#pragma unroll
            for (int mt = 0; mt < 2; mt++)
#pragma unroll
                for (int nt = 0; nt < 2; nt++)
                    acc[mt][nt] = __builtin_amdgcn_mfma_f32_32x32x16_bf16(
                        af[mt], bf[nt], acc[mt][nt], 0, 0, 0);
        }
        __syncthreads();
    }

    // C-reg j within rg maps to row rowg+j -> per-ROW denominator RL[rowg+j]
#pragma unroll
    for (int mt = 0; mt < 2; mt++)
#pragma unroll
        for (int nt = 0; nt < 2; nt++) {
            const int colg = tn * TN + wn * 64 + nt * 32 + lm;
#pragma unroll
            for (int rg = 0; rg < 4; rg++) {
                const int rowg = tm * TM + wm * 64 + mt * 32 + rg * 8 + 4 * lk;
                const float* rlp = RL + (size_t)batch * Nn + rowg;
                float* p = out + (size_t)batch * Nn * Dd + (size_t)rowg * Dd + colg;
#pragma unroll
                for (int j = 0; j < 4; j++)
                    p[(size_t)j * Dd] = acc[mt][nt][rg * 4 + j] * rlp[j];
            }
        }
}

extern "C" void kernel_launch(void* const* d_in, const int* in_sizes, int n_in,
                              void* d_out, int out_size, void* d_ws, size_t ws_size,
                              hipStream_t stream)
{
    const int Bn = 8, Nn = 2048, Dd = 1024;

    const float* x  = (const float*)d_in[0];
    const float* Wa = (const float*)d_in[1];
    const float* ba = (const float*)d_in[2];
    const float* Wo = (const float*)d_in[3];
    const float* bo = (const float*)d_in[4];
    float* out = (float*)d_out;

    const size_t nX = (size_t)Bn * Nn * Dd;
    const size_t nW = (size_t)Dd * Dd;
    const size_t nS = (size_t)Bn * Nn * Nn;
    const size_t nR = (size_t)Bn * Nn;        // 16384 rows

    bf16_t* xb  = (bf16_t*)d_ws;          // [B, N, D] bf16
    bf16_t* Wab = xb + nX;                // [D, D]
    bf16_t* Wob = Wab + nW;               // [D, D]
    bf16_t* key = Wob + nW;               // [B, N, D]
    bf16_t* vT  = key + nX;               // [B, D, N]
    bf16_t* S   = vT + nX;                // [B, N, N]
    float*  Mx  = (float*)(S + nS);       // [B*N]
    float*  RL  = Mx + nR;                // [B*N]
    const size_t needed = (nX * 3 + nW * 2 + nS) * sizeof(bf16_t) + 2 * nR * sizeof(float);
    if (ws_size < needed)
        fprintf(stderr, "kernel_launch: ws too small: have %zu need %zu\n", ws_size, needed);

    const dim3 blk(256);
    const long long sXN = (long long)Nn * Dd;
    const long long sS  = (long long)Nn * Nn;

    cvt_f32_bf16<<<dim3(16384), blk, 0, stream>>>(x, xb, (int)nX);
    cvt_f32_bf16<<<dim3(1024), blk, 0, stream>>>(Wa, Wab, (int)nW);
    cvt_f32_bf16<<<dim3(1024), blk, 0, stream>>>(Wo, Wob, (int)nW);

    // key = x@Wa^T+ba ; vT = (x@Wo^T+bo)^T
    gemm_kv<<<dim3(Bn * 16 * 16), blk, 0, stream>>>(
        xb, Wab, Wob, ba, bo, key, vT, Nn, Dd, Dd);

    // S = (x @ key^T) / 32
    gemm_scores<<<dim3(Bn * 16 * 16), blk, 0, stream>>>(
        xb, key, S, 0.03125f, Nn, Dd, sXN, sXN, sS, 16, 16);

    // per-row max and 1/sum(exp)
    row_stats<<<dim3(Bn * Nn), blk, 0, stream>>>(S, Mx, RL);

    // out = softmax(S) @ V, softmax fused via (Mx, RL)
    gemm_out<<<dim3(Bn * 16 * 8), blk, 0, stream>>>(
        S, vT, Mx, RL, out, Nn, Dd);
}

// Round 6
// 426.876 us; speedup vs baseline: 1.0428x; 1.0428x over previous
//
#include <hip/hip_runtime.h>
#include <hip/hip_bf16.h>
#include <cstdio>

typedef __bf16 bf16_t;
typedef __bf16 bf16x8 __attribute__((ext_vector_type(8)));
typedef __bf16 bf16x4 __attribute__((ext_vector_type(4)));
typedef float  f32x16 __attribute__((ext_vector_type(16)));

#define TM 128
#define TN 128
#define BK 32

// ---- merged f32 -> bf16 convert for x, Wa, Wo (one dispatch) ---------------
__global__ __launch_bounds__(256)
void cvt_all(const float* __restrict__ x,  bf16_t* __restrict__ xb,  int nX,
             const float* __restrict__ Wa, bf16_t* __restrict__ Wab,
             const float* __restrict__ Wo, bf16_t* __restrict__ Wob, int nW)
{
    const int nT = nX + 2 * nW;
    for (int i = (blockIdx.x * 256 + threadIdx.x) * 4; i < nT; i += gridDim.x * 256 * 4) {
        const float* src; bf16_t* dst; int off;
        if (i < nX)            { src = x;  dst = xb;  off = i; }
        else if (i < nX + nW)  { src = Wa; dst = Wab; off = i - nX; }
        else                   { src = Wo; dst = Wob; off = i - nX - nW; }
        const float4 v = *(const float4*)(src + off);
        bf16x4 o;
        o[0] = (bf16_t)v.x; o[1] = (bf16_t)v.y; o[2] = (bf16_t)v.z; o[3] = (bf16_t)v.w;
        *(bf16x4*)(dst + off) = o;
    }
}

// ---- BK=32 staging (R3-proven) ---------------------------------------------
// LDS rows of 32 bf16 (64 B = 4 chunks of 16 B); chunk c of row r at slot
// c ^ ((r>>1)&3). Swizzle applied to the per-lane GLOBAL src addr; LDS dest
// is wave-uniform base + lane*16 (HW rule for global_load_lds).
__device__ __forceinline__ void stage_tiles(
    const bf16_t* __restrict__ Ab, const bf16_t* __restrict__ Bb,
    bf16_t* As, bf16_t* Bs, int k0, int K, int t, int w)
{
    const int src_c = (t & 3) ^ ((t >> 3) & 3);       // swizzled source chunk
#pragma unroll
    for (int rd = 0; rd < 2; rd++) {
        const int row = rd * 64 + (t >> 2);
        __builtin_amdgcn_global_load_lds(
            (const __attribute__((address_space(1))) void*)(Ab + (size_t)row * K + k0 + src_c * 8),
            (__attribute__((address_space(3))) void*)(&As[(rd * 64 + w * 16) * 32]), 16, 0, 0);
        __builtin_amdgcn_global_load_lds(
            (const __attribute__((address_space(1))) void*)(Bb + (size_t)row * K + k0 + src_c * 8),
            (__attribute__((address_space(3))) void*)(&Bs[(rd * 64 + w * 16) * 32]), 16, 0, 0);
    }
}

__device__ __forceinline__ int fidx(int row, int c)   // chunk c in [0,4)
{
    return row * 32 + ((c ^ ((row >> 1) & 3)) * 8);
}

#define ACC_INIT(acc)                                            \
    _Pragma("unroll") for (int i = 0; i < 2; i++)                \
    _Pragma("unroll") for (int j = 0; j < 2; j++)                \
    _Pragma("unroll") for (int e = 0; e < 16; e++) acc[i][j][e] = 0.f;

#define MAINLOOP_STEP(As, Bs)                                                     \
    {                                                                             \
        bf16x8 af[2][2], bfr[2][2];                                               \
        _Pragma("unroll") for (int ks = 0; ks < 2; ks++) {                        \
            const int c = ks * 2 + lk;                                            \
            _Pragma("unroll") for (int mt = 0; mt < 2; mt++)                      \
                af[ks][mt] = *(const bf16x8*)&As[fidx(wm * 64 + mt * 32 + lm, c)];\
            _Pragma("unroll") for (int nt = 0; nt < 2; nt++)                      \
                bfr[ks][nt] = *(const bf16x8*)&Bs[fidx(wn * 64 + nt * 32 + lm, c)];\
        }                                                                         \
        _Pragma("unroll") for (int ks = 0; ks < 2; ks++)                          \
        _Pragma("unroll") for (int mt = 0; mt < 2; mt++)                          \
        _Pragma("unroll") for (int nt = 0; nt < 2; nt++)                          \
            acc[mt][nt] = __builtin_amdgcn_mfma_f32_32x32x16_bf16(                \
                af[ks][mt], bfr[ks][nt], acc[mt][nt], 0, 0, 0);                   \
    }

// ---- scores GEMM: C = (A @ Bm^T) * scale, bf16 write -----------------------
__global__ __launch_bounds__(256)
void gemm_scores(const bf16_t* __restrict__ A, const bf16_t* __restrict__ Bm,
                 bf16_t* __restrict__ C, float scale, int Ncols, int K,
                 long long strideA, long long strideB, long long strideC,
                 int tiles_m, int tiles_n)
{
    __shared__ bf16_t As[TM * BK];
    __shared__ bf16_t Bs[TN * BK];

    const int t    = threadIdx.x;
    const int w    = t >> 6;
    const int lane = t & 63;
    const int wm = w >> 1, wn = w & 1;
    const int lm = lane & 31;
    const int lk = lane >> 5;

    const int per_batch = tiles_m * tiles_n;
    const int batch = blockIdx.x / per_batch;
    const int rest  = blockIdx.x % per_batch;
    const int tm    = rest % tiles_m;
    const int tn    = rest / tiles_m;

    const bf16_t* Ab = A + (size_t)batch * strideA + (size_t)tm * TM * K;
    const bf16_t* Bb = Bm + (size_t)batch * strideB + (size_t)tn * TN * K;

    f32x16 acc[2][2];
    ACC_INIT(acc)

    for (int k0 = 0; k0 < K; k0 += BK) {
        stage_tiles(Ab, Bb, As, Bs, k0, K, t, w);
        __syncthreads();
        MAINLOOP_STEP(As, Bs)
        __syncthreads();
    }

    // 32x32 C/D: col = lane&31, row = (reg&3) + 8*(reg>>2) + 4*(lane>>5)
#pragma unroll
    for (int mt = 0; mt < 2; mt++)
#pragma unroll
        for (int nt = 0; nt < 2; nt++) {
            const int colg = tn * TN + wn * 64 + nt * 32 + lm;
#pragma unroll
            for (int rg = 0; rg < 4; rg++) {
                const int rowg = tm * TM + wm * 64 + mt * 32 + rg * 8 + 4 * lk;
                bf16_t* p = C + (size_t)batch * strideC + (size_t)rowg * Ncols + colg;
#pragma unroll
                for (int j = 0; j < 4; j++)
                    p[(size_t)j * Ncols] = (bf16_t)(acc[mt][nt][rg * 4 + j] * scale);
            }
        }
}

// ---- fused key/value GEMM ---------------------------------------------------
__global__ __launch_bounds__(256)
void gemm_kv(const bf16_t* __restrict__ A,
             const bf16_t* __restrict__ Wa, const bf16_t* __restrict__ Wo,
             const float* __restrict__ ba, const float* __restrict__ bo,
             bf16_t* __restrict__ key, bf16_t* __restrict__ vT,
             int Nn, int Dd, int K)
{
    __shared__ bf16_t As[TM * BK];
    __shared__ bf16_t Bs[TN * BK];

    const int t    = threadIdx.x;
    const int w    = t >> 6;
    const int lane = t & 63;
    const int wm = w >> 1, wn = w & 1;
    const int lm = lane & 31;
    const int lk = lane >> 5;

    const int tiles_m = Nn / TM;             // 16
    const int per_batch = tiles_m * 16;      // 8 key-tiles + 8 value-tiles
    const int batch = blockIdx.x / per_batch;
    const int rest  = blockIdx.x % per_batch;
    const int tm    = rest % tiles_m;
    const int tn    = rest / tiles_m;
    const bool isK  = (tn < 8);

    const bf16_t* Ab = A + (size_t)batch * Nn * K + (size_t)tm * TM * K;
    const bf16_t* Bb = (isK ? Wa + (size_t)tn * TN * K
                            : Wo + (size_t)(tn - 8) * TN * K);
    const float* bias = isK ? ba : bo;

    f32x16 acc[2][2];
    ACC_INIT(acc)

    for (int k0 = 0; k0 < K; k0 += BK) {
        stage_tiles(Ab, Bb, As, Bs, k0, K, t, w);
        __syncthreads();
        MAINLOOP_STEP(As, Bs)
        __syncthreads();
    }

#pragma unroll
    for (int mt = 0; mt < 2; mt++)
#pragma unroll
        for (int nt = 0; nt < 2; nt++) {
            const int cw = (tn & 7) * TN + wn * 64 + nt * 32 + lm;  // col in [0,1024)
            const float bv = bias[cw];                               // per-col (same all j)
#pragma unroll
            for (int rg = 0; rg < 4; rg++) {
                const int rowg = tm * TM + wm * 64 + mt * 32 + rg * 8 + 4 * lk;
                if (isK) {
                    bf16_t* p = key + (size_t)batch * Nn * Dd + (size_t)rowg * Dd + cw;
#pragma unroll
                    for (int j = 0; j < 4; j++)
                        p[(size_t)j * Dd] = (bf16_t)(acc[mt][nt][rg * 4 + j] + bv);
                } else {
                    // transposed: 4 regs = 4 consecutive rows -> 8B packed store
                    bf16_t* p = vT + (size_t)batch * Dd * Nn + (size_t)cw * Nn + rowg;
                    bf16x4 pk;
#pragma unroll
                    for (int j = 0; j < 4; j++)
                        pk[j] = (bf16_t)(acc[mt][nt][rg * 4 + j] + bv);
                    *(bf16x4*)p = pk;
                }
            }
        }
}

// ---- in-place normalizing row softmax (rows of 2048 bf16) ------------------
__global__ __launch_bounds__(256)
void softmax_rows(bf16_t* __restrict__ S)
{
    __shared__ float red[8];
    const int t = threadIdx.x;
    const int w = t >> 6;
    const int lane = t & 63;
    bf16_t* p = S + (size_t)blockIdx.x * 2048;

    bf16x8 v = *(const bf16x8*)&p[t * 8];
    float x[8];
    float m = -1e30f;
#pragma unroll
    for (int i = 0; i < 8; i++) { x[i] = (float)v[i]; m = fmaxf(m, x[i]); }
#pragma unroll
    for (int off = 32; off >= 1; off >>= 1) m = fmaxf(m, __shfl_xor(m, off));
    if (lane == 0) red[w] = m;
    __syncthreads();
    m = fmaxf(fmaxf(red[0], red[1]), fmaxf(red[2], red[3]));

    float s = 0.f;
#pragma unroll
    for (int i = 0; i < 8; i++) { x[i] = __expf(x[i] - m); s += x[i]; }
#pragma unroll
    for (int off = 32; off >= 1; off >>= 1) s += __shfl_xor(s, off);
    if (lane == 0) red[4 + w] = s;
    __syncthreads();
    const float inv = 1.f / (red[4] + red[5] + red[6] + red[7]);

    bf16x8 o;
#pragma unroll
    for (int i = 0; i < 8; i++) o[i] = (bf16_t)(x[i] * inv);
    *(bf16x8*)&p[t * 8] = o;
}

// ---- out GEMM: out = P @ (vT)^T, f32 write ---------------------------------
__global__ __launch_bounds__(256)
void gemm_out(const bf16_t* __restrict__ P, const bf16_t* __restrict__ vT,
              float* __restrict__ out, int Nn, int Dd)
{
    __shared__ bf16_t As[TM * BK];
    __shared__ bf16_t Bs[TN * BK];

    const int t    = threadIdx.x;
    const int w    = t >> 6;
    const int lane = t & 63;
    const int wm = w >> 1, wn = w & 1;
    const int lm = lane & 31;
    const int lk = lane >> 5;

    const int tiles_m = Nn / TM;               // 16
    const int tiles_n = Dd / TN;               // 8
    const int per_batch = tiles_m * tiles_n;
    const int batch = blockIdx.x / per_batch;
    const int rest  = blockIdx.x % per_batch;
    const int tm    = rest % tiles_m;
    const int tn    = rest / tiles_m;

    const int K = Nn;   // 2048
    const bf16_t* Ab = P + (size_t)batch * Nn * Nn + (size_t)tm * TM * K;
    const bf16_t* Bb = vT + (size_t)batch * Dd * Nn + (size_t)tn * TN * K;

    f32x16 acc[2][2];
    ACC_INIT(acc)

    for (int k0 = 0; k0 < K; k0 += BK) {
        stage_tiles(Ab, Bb, As, Bs, k0, K, t, w);
        __syncthreads();
        MAINLOOP_STEP(As, Bs)
        __syncthreads();
    }

#pragma unroll
    for (int mt = 0; mt < 2; mt++)
#pragma unroll
        for (int nt = 0; nt < 2; nt++) {
            const int colg = tn * TN + wn * 64 + nt * 32 + lm;
#pragma unroll
            for (int rg = 0; rg < 4; rg++) {
                const int rowg = tm * TM + wm * 64 + mt * 32 + rg * 8 + 4 * lk;
                float* p = out + (size_t)batch * Nn * Dd + (size_t)rowg * Dd + colg;
#pragma unroll
                for (int j = 0; j < 4; j++)
                    p[(size_t)j * Dd] = acc[mt][nt][rg * 4 + j];
            }
        }
}

extern "C" void kernel_launch(void* const* d_in, const int* in_sizes, int n_in,
                              void* d_out, int out_size, void* d_ws, size_t ws_size,
                              hipStream_t stream)
{
    const int Bn = 8, Nn = 2048, Dd = 1024;

    const float* x  = (const float*)d_in[0];
    const float* Wa = (const float*)d_in[1];
    const float* ba = (const float*)d_in[2];
    const float* Wo = (const float*)d_in[3];
    const float* bo = (const float*)d_in[4];
    float* out = (float*)d_out;

    const size_t nX = (size_t)Bn * Nn * Dd;
    const size_t nW = (size_t)Dd * Dd;
    const size_t nS = (size_t)Bn * Nn * Nn;

    bf16_t* xb  = (bf16_t*)d_ws;          // [B, N, D] bf16
    bf16_t* Wab = xb + nX;                // [D, D]
    bf16_t* Wob = Wab + nW;               // [D, D]
    bf16_t* key = Wob + nW;               // [B, N, D]
    bf16_t* vT  = key + nX;               // [B, D, N]
    bf16_t* S   = vT + nX;                // [B, N, N]
    const size_t needed = (nX * 3 + nW * 2 + nS) * sizeof(bf16_t);
    if (ws_size < needed)
        fprintf(stderr, "kernel_launch: ws too small: have %zu need %zu\n", ws_size, needed);

    const dim3 blk(256);
    const long long sXN = (long long)Nn * Dd;
    const long long sS  = (long long)Nn * Nn;

    // one merged convert dispatch (x, Wa, Wo)
    cvt_all<<<dim3(18432), blk, 0, stream>>>(x, xb, (int)nX, Wa, Wab, Wo, Wob, (int)nW);

    // key = x@Wa^T+ba ; vT = (x@Wo^T+bo)^T
    gemm_kv<<<dim3(Bn * 16 * 16), blk, 0, stream>>>(
        xb, Wab, Wob, ba, bo, key, vT, Nn, Dd, Dd);

    // S = (x @ key^T) / 32
    gemm_scores<<<dim3(Bn * 16 * 16), blk, 0, stream>>>(
        xb, key, S, 0.03125f, Nn, Dd, sXN, sXN, sS, 16, 16);

    // P = softmax(S) in place
    softmax_rows<<<dim3(Bn * Nn), blk, 0, stream>>>(S);

    // out = P @ (vT)^T   [B,N,D] f32
    gemm_out<<<dim3(Bn * 16 * 8), blk, 0, stream>>>(
        S, vT, out, Nn, Dd);
}